// Round 2
// baseline (143.418 us; speedup 1.0000x reference)
//
#include <hip/hip_runtime.h>
#include <hip/hip_bf16.h>

// ---- problem constants ----
#define NG 1024
#define IMW 256
#define IMH 192
#define FXc 220.0f
#define FYc 220.0f
#define CXc 128.0f
#define CYc 96.0f
#define NEARc 0.01f
#define FARc 10.0f
#define ALPHA_THRc 1e-5f

// SH constants
#define SH_C0 0.28209479177387814f
#define SH_C1 0.4886025119029199f
#define SH_C2_0 1.0925484305920792f
#define SH_C2_1 (-1.0925484305920792f)
#define SH_C2_2 0.31539156525252005f
#define SH_C2_3 (-1.0925484305920792f)
#define SH_C2_4 0.5462742152960396f
#define SH_C3_0 (-0.5900435899266435f)
#define SH_C3_1 2.890611442640554f
#define SH_C3_2 (-0.4570457994644658f)
#define SH_C3_3 0.3731763325901154f
#define SH_C3_4 (-0.4570457994644658f)
#define SH_C3_5 1.445305721320277f
#define SH_C3_6 (-0.5900435899266435f)

// ws layout (bytes):
//   raw float arrays [10][NG]  @ 0        : u,v,A,B,C,op,z,r,g,b   (40960 B)
//   s0 float4[NG]              @ 40960    : (u,v,A,B)
//   s1 float4[NG]              @ 57344    : (C,op,r,g)
//   s2 float4[NG]              @ 73728    : (b,z,0,0)
//   n_valid int                @ 90112

__global__ __launch_bounds__(256)
void gs_prep(const float* __restrict__ pos, const float* __restrict__ rot,
             const float* __restrict__ scl, const float* __restrict__ opac,
             const float* __restrict__ sh,  const float* __restrict__ Twc,
             float* __restrict__ raw) {
    int i = blockIdx.x * 256 + threadIdx.x;
    if (i >= NG) return;

    float p0 = pos[i*3+0], p1 = pos[i*3+1], p2 = pos[i*3+2];
    float xc = Twc[0]*p0 + Twc[1]*p1 + Twc[2]*p2  + Twc[3];
    float yc = Twc[4]*p0 + Twc[5]*p1 + Twc[6]*p2  + Twc[7];
    float zc = Twc[8]*p0 + Twc[9]*p1 + Twc[10]*p2 + Twc[11];

    float az = fabsf(zc);
    const float xfac = fmaxf(CXc/FXc, (IMW - CXc)/FXc) * 1.1f;   // (1+MARGIN)
    const float yfac = fmaxf(CYc/FYc, (IMH - CYc)/FYc) * 1.1f;
    bool valid = (az > NEARc) && (az < FARc) &&
                 (fabsf(xc) < az * xfac) && (fabsf(yc) < az * yfac);

    float zs = (az < 1e-8f) ? 1e-8f : zc;
    float iz = 1.0f / zs;
    float u = FXc * xc * iz + CXc;
    float v = FYc * yc * iz + CYc;

    // quaternion -> R
    float qw = rot[i*4+0], qx = rot[i*4+1], qy = rot[i*4+2], qz = rot[i*4+3];
    float qn = sqrtf(qw*qw + qx*qx + qy*qy + qz*qz) + 1e-12f;
    float inq = 1.0f / qn;
    qw *= inq; qx *= inq; qy *= inq; qz *= inq;
    float R00 = 1.0f - 2.0f*(qy*qy + qz*qz);
    float R01 = 2.0f*(qx*qy - qw*qz);
    float R02 = 2.0f*(qx*qz + qw*qy);
    float R10 = 2.0f*(qx*qy + qw*qz);
    float R11 = 1.0f - 2.0f*(qx*qx + qz*qz);
    float R12 = 2.0f*(qy*qz - qw*qx);
    float R20 = 2.0f*(qx*qz - qw*qy);
    float R21 = 2.0f*(qy*qz + qw*qx);
    float R22 = 1.0f - 2.0f*(qx*qx + qy*qy);

    float s0 = expf(scl[i*3+0]);
    float s1 = expf(scl[i*3+1]);
    float s2 = expf(scl[i*3+2]);
    float M00 = R00*s0, M01 = R01*s1, M02 = R02*s2;
    float M10 = R10*s0, M11 = R11*s1, M12 = R12*s2;
    float M20 = R20*s0, M21 = R21*s1, M22 = R22*s2;

    // cov3d = M M^T (symmetric)
    float S00 = M00*M00 + M01*M01 + M02*M02;
    float S01 = M00*M10 + M01*M11 + M02*M12;
    float S02 = M00*M20 + M01*M21 + M02*M22;
    float S11 = M10*M10 + M11*M11 + M12*M12;
    float S12 = M10*M20 + M11*M21 + M12*M22;
    float S22 = M20*M20 + M21*M21 + M22*M22;

    // J (2x3), cov2d = J S J^T
    float j00 = FXc * iz,  j02 = -FXc * xc * iz * iz;
    float j11 = FYc * iz,  j12 = -FYc * yc * iz * iz;
    float c00 = j00*j00*S00 + 2.0f*j00*j02*S02 + j02*j02*S22 + 0.3f;
    float c01 = j00*j11*S01 + j00*j12*S02 + j02*j11*S12 + j02*j12*S22;
    float c11 = j11*j11*S11 + 2.0f*j11*j12*S12 + j12*j12*S22 + 0.3f;
    float det = fmaxf(c00*c11 - c01*c01, 1e-12f);
    float idet = 1.0f / det;
    float Ai = c11 * idet;
    float Bi = -c01 * idet;
    float Ci = c00 * idet;

    float op = valid ? opac[i] : 0.0f;

    // view dir
    float pn = sqrtf(xc*xc + yc*yc + zc*zc) + 1e-12f;
    float ipn = 1.0f / pn;
    float dx = xc*ipn, dy = yc*ipn, dz = zc*ipn;
    float xx = dx*dx, yy = dy*dy, zz = dz*dz;
    float xy = dx*dy, yz = dy*dz, xz = dx*dz;

    const float* s = sh + i*48;
    float col[3];
#pragma unroll
    for (int ch = 0; ch < 3; ++ch) {
        float c = SH_C0*s[0+ch] - SH_C1*dy*s[3+ch] + SH_C1*dz*s[6+ch] - SH_C1*dx*s[9+ch];
        c += SH_C2_0*xy*s[12+ch] + SH_C2_1*yz*s[15+ch] + SH_C2_2*(2.0f*zz-xx-yy)*s[18+ch]
           + SH_C2_3*xz*s[21+ch] + SH_C2_4*(xx-yy)*s[24+ch];
        c += SH_C3_0*dy*(3.0f*xx-yy)*s[27+ch] + SH_C3_1*xy*dz*s[30+ch]
           + SH_C3_2*dy*(4.0f*zz-xx-yy)*s[33+ch] + SH_C3_3*dz*(2.0f*zz-3.0f*xx-3.0f*yy)*s[36+ch]
           + SH_C3_4*dx*(4.0f*zz-xx-yy)*s[39+ch] + SH_C3_5*dz*(xx-yy)*s[42+ch]
           + SH_C3_6*dx*(xx-3.0f*yy)*s[45+ch];
        col[ch] = fminf(fmaxf(c + 0.5f, 0.0f), 1.0f);
    }

    raw[0*NG + i] = u;
    raw[1*NG + i] = v;
    raw[2*NG + i] = Ai;
    raw[3*NG + i] = Bi;
    raw[4*NG + i] = Ci;
    raw[5*NG + i] = op;
    raw[6*NG + i] = zc;
    raw[7*NG + i] = col[0];
    raw[8*NG + i] = col[1];
    raw[9*NG + i] = col[2];
}

// Counting sort (ascending z among kept), with compaction. 4 blocks x 256.
__global__ __launch_bounds__(256)
void gs_sort(const float* __restrict__ raw,
             float4* __restrict__ s0, float4* __restrict__ s1, float4* __restrict__ s2,
             int* __restrict__ nvp) {
    __shared__ float zl[NG];
    __shared__ int   kl[NG];
    int t = threadIdx.x;
    int i = blockIdx.x * 256 + t;

    for (int j = t; j < NG; j += 256) {
        zl[j] = raw[6*NG + j];
        kl[j] = raw[5*NG + j] > 0.0f ? 1 : 0;
    }
    __syncthreads();

    float zi = zl[i];
    int rank = 0, cnt = 0;
    // ascending z among kept; ties: larger original index first (matches
    // reverse of stable argsort(-z))
    for (int j = 0; j < NG; ++j) {
        int kj = kl[j];
        float zj = zl[j];
        cnt += kj;
        bool before = (zj < zi) || (zj == zi && j > i);
        rank += (kj && before) ? 1 : 0;
    }
    if (i == 0) *nvp = cnt;

    if (kl[i]) {
        float u  = raw[0*NG + i], v  = raw[1*NG + i];
        float Ai = raw[2*NG + i], Bi = raw[3*NG + i], Ci = raw[4*NG + i];
        float op = raw[5*NG + i], z  = raw[6*NG + i];
        float r  = raw[7*NG + i], g  = raw[8*NG + i], b = raw[9*NG + i];
        s0[rank] = make_float4(u, v, Ai, Bi);
        s1[rank] = make_float4(Ci, op, r, g);
        s2[rank] = make_float4(b, z, 0.0f, 0.0f);
    }
}

// Rasterize: one pixel per thread, 16x16 tile per block, gaussians staged in
// LDS in chunks of 256, front-to-back compositing.
__global__ __launch_bounds__(256)
void gs_raster(const float4* __restrict__ s0, const float4* __restrict__ s1,
               const float4* __restrict__ s2, const int* __restrict__ nvp,
               float* __restrict__ out) {
    __shared__ float4 l0[256], l1[256], l2[256];

    int x = blockIdx.x * 16 + threadIdx.x;
    int y = blockIdx.y * 16 + threadIdx.y;
    float px = (float)x + 0.5f;
    float py = (float)y + 0.5f;
    int t = threadIdx.y * 16 + threadIdx.x;

    int nv = *nvp;

    float T = 1.0f;
    float cr = 0.0f, cg = 0.0f, cb = 0.0f, cd = 0.0f;
    bool done = false;

    for (int base = 0; base < nv; base += 256) {
        int cnt = min(256, nv - base);
        __syncthreads();
        if (t < cnt) {
            l0[t] = s0[base + t];
            l1[t] = s1[base + t];
            l2[t] = s2[base + t];
        }
        __syncthreads();
        if (!done) {
            for (int j = 0; j < cnt; ++j) {
                float4 a0 = l0[j];
                float4 a1 = l1[j];
                float4 a2 = l2[j];
                float dx = px - a0.x;
                float dy = py - a0.y;
                float pw = -0.5f * (a0.z * dx * dx + a1.x * dy * dy) - a0.w * dx * dy;
                pw = fminf(pw, 0.0f);
                float alpha = fminf(0.99f, a1.y * __expf(pw));
                if (alpha >= ALPHA_THRc) {
                    float w = alpha * T;
                    cr += w * a1.z;
                    cg += w * a1.w;
                    cb += w * a2.x;
                    cd += w * a2.y;
                    T *= 1.0f - alpha;
                }
                if (__all(T < 1e-4f)) { done = true; break; }
            }
        }
    }

    int idx = y * IMW + x;
    out[idx*3 + 0] = cr;
    out[idx*3 + 1] = cg;
    out[idx*3 + 2] = cb;
    out[IMH*IMW*3 + idx] = cd;
}

extern "C" void kernel_launch(void* const* d_in, const int* in_sizes, int n_in,
                              void* d_out, int out_size, void* d_ws, size_t ws_size,
                              hipStream_t stream) {
    const float* pos  = (const float*)d_in[0];
    const float* rot  = (const float*)d_in[1];
    const float* scl  = (const float*)d_in[2];
    const float* opac = (const float*)d_in[3];
    const float* sh   = (const float*)d_in[4];
    const float* Twc  = (const float*)d_in[5];
    float* out = (float*)d_out;

    char* ws = (char*)d_ws;
    float*  raw = (float*)ws;                       // 10*NG floats
    float4* s0  = (float4*)(ws + 40960);
    float4* s1  = (float4*)(ws + 57344);
    float4* s2  = (float4*)(ws + 73728);
    int*    nvp = (int*)(ws + 90112);

    gs_prep<<<dim3(NG/256), dim3(256), 0, stream>>>(pos, rot, scl, opac, sh, Twc, raw);
    gs_sort<<<dim3(NG/256), dim3(256), 0, stream>>>(raw, s0, s1, s2, nvp);
    gs_raster<<<dim3(IMW/16, IMH/16), dim3(16, 16), 0, stream>>>(s0, s1, s2, nvp, out);
}

// Round 3
// 31.480 us; speedup vs baseline: 4.5559x; 4.5559x over previous
//
#include <hip/hip_runtime.h>
#include <hip/hip_bf16.h>

// ---- problem constants ----
#define NG 1024
#define IMW 256
#define IMH 192
#define NPIX (IMW*IMH)
#define FXc 220.0f
#define FYc 220.0f
#define CXc 128.0f
#define CYc 96.0f
#define NEARc 0.01f
#define FARc 10.0f
#define ALPHA_THRc 1e-5f

// SH constants
#define SH_C0 0.28209479177387814f
#define SH_C1 0.4886025119029199f
#define SH_C2_0 1.0925484305920792f
#define SH_C2_1 (-1.0925484305920792f)
#define SH_C2_2 0.31539156525252005f
#define SH_C2_3 (-1.0925484305920792f)
#define SH_C2_4 0.5462742152960396f
#define SH_C3_0 (-0.5900435899266435f)
#define SH_C3_1 2.890611442640554f
#define SH_C3_2 (-0.4570457994644658f)
#define SH_C3_3 0.3731763325901154f
#define SH_C3_4 (-0.4570457994644658f)
#define SH_C3_5 1.445305721320277f
#define SH_C3_6 (-0.5900435899266435f)

// ws layout (bytes):
//   raw float arrays [12][NG]  @ 0      : u,v,A,B,C,op,z,r,g,b,rx,ry  (49152 B)
//   s0 float4[NG]              @ 49152  : (u,v,A,B)
//   s1 float4[NG]              @ 65536  : (C,op,r,g)
//   s2 float4[NG]              @ 81920  : (b,z,rx,ry)
//   n_valid int                @ 98304
//   seg buffers (5 arrays)     @ 98432  : cr,cg,cb,cd,ct each SEG*NPIX floats

__global__ __launch_bounds__(64)
void gs_prep(const float* __restrict__ pos, const float* __restrict__ rot,
             const float* __restrict__ scl, const float* __restrict__ opac,
             const float* __restrict__ sh,  const float* __restrict__ Twc,
             float* __restrict__ raw) {
    int i = blockIdx.x * 64 + threadIdx.x;
    if (i >= NG) return;

    float p0 = pos[i*3+0], p1 = pos[i*3+1], p2 = pos[i*3+2];
    float xc = Twc[0]*p0 + Twc[1]*p1 + Twc[2]*p2  + Twc[3];
    float yc = Twc[4]*p0 + Twc[5]*p1 + Twc[6]*p2  + Twc[7];
    float zc = Twc[8]*p0 + Twc[9]*p1 + Twc[10]*p2 + Twc[11];

    float az = fabsf(zc);
    const float xfac = fmaxf(CXc/FXc, (IMW - CXc)/FXc) * 1.1f;   // (1+MARGIN)
    const float yfac = fmaxf(CYc/FYc, (IMH - CYc)/FYc) * 1.1f;
    bool valid = (az > NEARc) && (az < FARc) &&
                 (fabsf(xc) < az * xfac) && (fabsf(yc) < az * yfac);

    float zs = (az < 1e-8f) ? 1e-8f : zc;
    float iz = 1.0f / zs;
    float u = FXc * xc * iz + CXc;
    float v = FYc * yc * iz + CYc;

    // quaternion -> R
    float qw = rot[i*4+0], qx = rot[i*4+1], qy = rot[i*4+2], qz = rot[i*4+3];
    float qn = sqrtf(qw*qw + qx*qx + qy*qy + qz*qz) + 1e-12f;
    float inq = 1.0f / qn;
    qw *= inq; qx *= inq; qy *= inq; qz *= inq;
    float R00 = 1.0f - 2.0f*(qy*qy + qz*qz);
    float R01 = 2.0f*(qx*qy - qw*qz);
    float R02 = 2.0f*(qx*qz + qw*qy);
    float R10 = 2.0f*(qx*qy + qw*qz);
    float R11 = 1.0f - 2.0f*(qx*qx + qz*qz);
    float R12 = 2.0f*(qy*qz - qw*qx);
    float R20 = 2.0f*(qx*qz - qw*qy);
    float R21 = 2.0f*(qy*qz + qw*qx);
    float R22 = 1.0f - 2.0f*(qx*qx + qy*qy);

    float s0 = expf(scl[i*3+0]);
    float s1 = expf(scl[i*3+1]);
    float s2 = expf(scl[i*3+2]);
    float M00 = R00*s0, M01 = R01*s1, M02 = R02*s2;
    float M10 = R10*s0, M11 = R11*s1, M12 = R12*s2;
    float M20 = R20*s0, M21 = R21*s1, M22 = R22*s2;

    // cov3d = M M^T (symmetric)
    float S00 = M00*M00 + M01*M01 + M02*M02;
    float S01 = M00*M10 + M01*M11 + M02*M12;
    float S02 = M00*M20 + M01*M21 + M02*M22;
    float S11 = M10*M10 + M11*M11 + M12*M12;
    float S12 = M10*M20 + M11*M21 + M12*M22;
    float S22 = M20*M20 + M21*M21 + M22*M22;

    // J (2x3), cov2d = J S J^T
    float j00 = FXc * iz,  j02 = -FXc * xc * iz * iz;
    float j11 = FYc * iz,  j12 = -FYc * yc * iz * iz;
    float c00 = j00*j00*S00 + 2.0f*j00*j02*S02 + j02*j02*S22 + 0.3f;
    float c01 = j00*j11*S01 + j00*j12*S02 + j02*j11*S12 + j02*j12*S22;
    float c11 = j11*j11*S11 + 2.0f*j11*j12*S12 + j12*j12*S22 + 0.3f;
    float det = fmaxf(c00*c11 - c01*c01, 1e-12f);
    float idet = 1.0f / det;
    float Ai = c11 * idet;
    float Bi = -c01 * idet;
    float Ci = c00 * idet;

    float op = valid ? opac[i] : 0.0f;

    // conservative per-gaussian extent: alpha >= thr  =>  q <= Q
    // ellipse q = Q extreme along x: rx = sqrt(Q * c00); along y: sqrt(Q * c11)
    float Q = fmaxf(2.0f * logf(fmaxf(op, 1e-20f) * 1e5f), 0.0f);
    float rx = sqrtf(Q * c00) + 1e-3f;
    float ry = sqrtf(Q * c11) + 1e-3f;

    // view dir
    float pn = sqrtf(xc*xc + yc*yc + zc*zc) + 1e-12f;
    float ipn = 1.0f / pn;
    float dx = xc*ipn, dy = yc*ipn, dz = zc*ipn;
    float xx = dx*dx, yy = dy*dy, zz = dz*dz;
    float xy = dx*dy, yz = dy*dz, xz = dx*dz;

    const float* s = sh + i*48;
    float col[3];
#pragma unroll
    for (int ch = 0; ch < 3; ++ch) {
        float c = SH_C0*s[0+ch] - SH_C1*dy*s[3+ch] + SH_C1*dz*s[6+ch] - SH_C1*dx*s[9+ch];
        c += SH_C2_0*xy*s[12+ch] + SH_C2_1*yz*s[15+ch] + SH_C2_2*(2.0f*zz-xx-yy)*s[18+ch]
           + SH_C2_3*xz*s[21+ch] + SH_C2_4*(xx-yy)*s[24+ch];
        c += SH_C3_0*dy*(3.0f*xx-yy)*s[27+ch] + SH_C3_1*xy*dz*s[30+ch]
           + SH_C3_2*dy*(4.0f*zz-xx-yy)*s[33+ch] + SH_C3_3*dz*(2.0f*zz-3.0f*xx-3.0f*yy)*s[36+ch]
           + SH_C3_4*dx*(4.0f*zz-xx-yy)*s[39+ch] + SH_C3_5*dz*(xx-yy)*s[42+ch]
           + SH_C3_6*dx*(xx-3.0f*yy)*s[45+ch];
        col[ch] = fminf(fmaxf(c + 0.5f, 0.0f), 1.0f);
    }

    raw[0*NG + i]  = u;
    raw[1*NG + i]  = v;
    raw[2*NG + i]  = Ai;
    raw[3*NG + i]  = Bi;
    raw[4*NG + i]  = Ci;
    raw[5*NG + i]  = op;
    raw[6*NG + i]  = zc;
    raw[7*NG + i]  = col[0];
    raw[8*NG + i]  = col[1];
    raw[9*NG + i]  = col[2];
    raw[10*NG + i] = rx;
    raw[11*NG + i] = ry;
}

// Rank-based counting sort, 16 blocks x 256 threads. Packed uint64 keys
// (monotone z bits | tie-break), each block ranks 64 gaussians with the
// j-loop split 4-ways across waves.
__global__ __launch_bounds__(256)
void gs_sortc(const float* __restrict__ raw,
              float4* __restrict__ s0, float4* __restrict__ s1, float4* __restrict__ s2,
              int* __restrict__ nvp) {
    __shared__ unsigned long long keys[NG];
    __shared__ int pr[256];
    __shared__ int cntl;
    int t = threadIdx.x;
    if (t == 0) cntl = 0;
    __syncthreads();

#pragma unroll
    for (int p = 0; p < 4; ++p) {
        int j = t + p * 256;
        float z  = raw[6*NG + j];
        float op = raw[5*NG + j];
        bool keep = op > 0.0f;
        unsigned int zb = __float_as_uint(z);
        zb = (zb & 0x80000000u) ? ~zb : (zb | 0x80000000u);   // monotone float->uint
        unsigned long long k = keep
            ? ((unsigned long long)zb << 32) | (unsigned int)(NG - 1 - j)
            : ~0ull;
        keys[j] = k;
        unsigned long long mm = __ballot(keep);
        if ((t & 63) == 0) atomicAdd(&cntl, __popcll(mm));
    }
    __syncthreads();

    int il = t & 63;
    int jseg = t >> 6;                    // 0..3
    int i = blockIdx.x * 64 + il;
    unsigned long long ki = keys[i];
    int partial = 0;
    int jbase = jseg * 256;
#pragma unroll 4
    for (int j = jbase; j < jbase + 256; ++j)
        partial += (keys[j] < ki) ? 1 : 0;
    pr[t] = partial;
    __syncthreads();

    if (t < 64) {
        int i2 = blockIdx.x * 64 + t;
        int rank = pr[t] + pr[t+64] + pr[t+128] + pr[t+192];
        if (raw[5*NG + i2] > 0.0f) {
            float u  = raw[0*NG + i2], v  = raw[1*NG + i2];
            float Ai = raw[2*NG + i2], Bi = raw[3*NG + i2], Ci = raw[4*NG + i2];
            float op = raw[5*NG + i2], z  = raw[6*NG + i2];
            float r  = raw[7*NG + i2], g  = raw[8*NG + i2], b = raw[9*NG + i2];
            float rx = raw[10*NG + i2], ry = raw[11*NG + i2];
            s0[rank] = make_float4(u, v, Ai, Bi);
            s1[rank] = make_float4(Ci, op, r, g);
            s2[rank] = make_float4(b, z, rx, ry);
        }
        if (i2 == 0) *nvp = cntl;
    }
}

// Segmented rasterizer: grid (16,12,SEG). Block = 16x16 pixel tile x one depth
// segment. Stages segment chunk in LDS, ballot-compacts tile-overlapping
// gaussians (order-preserving), composites front-to-back within segment,
// writes per-segment partial (C, T) to ws.
__global__ __launch_bounds__(256)
void gs_raster_seg(const float4* __restrict__ s0, const float4* __restrict__ s1,
                   const float4* __restrict__ s2, const int* __restrict__ nvp,
                   int SEG,
                   float* __restrict__ cr, float* __restrict__ cg,
                   float* __restrict__ cb, float* __restrict__ cd,
                   float* __restrict__ ct) {
    __shared__ float4 l0[256], l1[256], l2[256];
    __shared__ unsigned short cidx[256];
    __shared__ int wbase[5];

    int x = blockIdx.x * 16 + threadIdx.x;
    int y = blockIdx.y * 16 + threadIdx.y;
    int s = blockIdx.z;
    float px = (float)x + 0.5f;
    float py = (float)y + 0.5f;
    int t = threadIdx.y * 16 + threadIdx.x;
    int lane = t & 63, w = t >> 6;

    float tx0 = (float)(blockIdx.x * 16) + 0.5f;
    float tx1 = tx0 + 15.0f;
    float ty0 = (float)(blockIdx.y * 16) + 0.5f;
    float ty1 = ty0 + 15.0f;

    int nv = *nvp;
    int per = (nv + SEG - 1) / SEG;
    int g0 = s * per;
    int g1 = min(nv, g0 + per);

    float T = 1.0f;
    float acr = 0.0f, acg = 0.0f, acb = 0.0f, acd = 0.0f;
    bool done = false;

    for (int base = g0; base < g1; base += 256) {
        int cnt = min(256, g1 - base);
        __syncthreads();
        if (t < cnt) {
            l0[t] = s0[base + t];
            l1[t] = s1[base + t];
            l2[t] = s2[base + t];
        }
        __syncthreads();

        // tile-overlap test + order-preserving ballot compaction
        bool pass = false;
        if (t < cnt) {
            float4 a0 = l0[t];
            float4 a2 = l2[t];
            pass = (a0.x + a2.z >= tx0) && (a0.x - a2.z <= tx1) &&
                   (a0.y + a2.w >= ty0) && (a0.y - a2.w <= ty1);
        }
        unsigned long long m = __ballot(pass);
        if (lane == 0) wbase[w] = __popcll(m);
        __syncthreads();
        if (t == 0) {
            int acc = 0;
#pragma unroll
            for (int k = 0; k < 4; ++k) { int c = wbase[k]; wbase[k] = acc; acc += c; }
            wbase[4] = acc;
        }
        __syncthreads();
        if (pass)
            cidx[wbase[w] + __popcll(m & ((1ull << lane) - 1ull))] = (unsigned short)t;
        __syncthreads();
        int mt = wbase[4];

        if (!done) {
            for (int j = 0; j < mt; ++j) {
                int id = cidx[j];
                float4 a0 = l0[id];
                float4 a1 = l1[id];
                float4 a2 = l2[id];
                float dx = px - a0.x;
                float dy = py - a0.y;
                float pw = -0.5f * (a0.z * dx * dx + a1.x * dy * dy) - a0.w * dx * dy;
                pw = fminf(pw, 0.0f);
                float alpha = fminf(0.99f, a1.y * __expf(pw));
                float aeff = (alpha >= ALPHA_THRc) ? alpha : 0.0f;
                float wgt = aeff * T;
                acr += wgt * a1.z;
                acg += wgt * a1.w;
                acb += wgt * a2.x;
                acd += wgt * a2.y;
                T *= 1.0f - aeff;
                if (__all(T < 1e-4f)) { done = true; break; }
            }
        }
    }

    int pix = y * IMW + x;
    size_t o = (size_t)s * NPIX + pix;
    cr[o] = acr;
    cg[o] = acg;
    cb[o] = acb;
    cd[o] = acd;
    ct[o] = T;
}

// Ordered affine combine over segments: C = sum_s (prod_{k<s} T_k) * C_s
__global__ __launch_bounds__(256)
void gs_combine(const float* __restrict__ cr, const float* __restrict__ cg,
                const float* __restrict__ cb, const float* __restrict__ cd,
                const float* __restrict__ ct, int SEG,
                float* __restrict__ out) {
    int p = blockIdx.x * 256 + threadIdx.x;
    if (p >= NPIX) return;
    float T = 1.0f, r = 0.0f, g = 0.0f, b = 0.0f, d = 0.0f;
    for (int s = 0; s < SEG; ++s) {
        size_t o = (size_t)s * NPIX + p;
        r += T * cr[o];
        g += T * cg[o];
        b += T * cb[o];
        d += T * cd[o];
        T *= ct[o];
    }
    out[p*3 + 0] = r;
    out[p*3 + 1] = g;
    out[p*3 + 2] = b;
    out[NPIX*3 + p] = d;
}

// Fallback (ws too small for segment buffers): direct single-pass raster.
__global__ __launch_bounds__(256)
void gs_raster_direct(const float4* __restrict__ s0, const float4* __restrict__ s1,
                      const float4* __restrict__ s2, const int* __restrict__ nvp,
                      float* __restrict__ out) {
    __shared__ float4 l0[256], l1[256], l2[256];
    int x = blockIdx.x * 16 + threadIdx.x;
    int y = blockIdx.y * 16 + threadIdx.y;
    float px = (float)x + 0.5f;
    float py = (float)y + 0.5f;
    int t = threadIdx.y * 16 + threadIdx.x;
    int nv = *nvp;
    float T = 1.0f, cr = 0.0f, cg = 0.0f, cb = 0.0f, cd = 0.0f;
    bool done = false;
    for (int base = 0; base < nv; base += 256) {
        int cnt = min(256, nv - base);
        __syncthreads();
        if (t < cnt) { l0[t] = s0[base+t]; l1[t] = s1[base+t]; l2[t] = s2[base+t]; }
        __syncthreads();
        if (!done) {
            for (int j = 0; j < cnt; ++j) {
                float4 a0 = l0[j], a1 = l1[j], a2 = l2[j];
                float dx = px - a0.x, dy = py - a0.y;
                float pw = -0.5f * (a0.z*dx*dx + a1.x*dy*dy) - a0.w*dx*dy;
                pw = fminf(pw, 0.0f);
                float alpha = fminf(0.99f, a1.y * __expf(pw));
                float aeff = (alpha >= ALPHA_THRc) ? alpha : 0.0f;
                float wgt = aeff * T;
                cr += wgt * a1.z; cg += wgt * a1.w; cb += wgt * a2.x; cd += wgt * a2.y;
                T *= 1.0f - aeff;
                if (__all(T < 1e-4f)) { done = true; break; }
            }
        }
    }
    int idx = y * IMW + x;
    out[idx*3+0] = cr; out[idx*3+1] = cg; out[idx*3+2] = cb;
    out[NPIX*3 + idx] = cd;
}

extern "C" void kernel_launch(void* const* d_in, const int* in_sizes, int n_in,
                              void* d_out, int out_size, void* d_ws, size_t ws_size,
                              hipStream_t stream) {
    const float* pos  = (const float*)d_in[0];
    const float* rot  = (const float*)d_in[1];
    const float* scl  = (const float*)d_in[2];
    const float* opac = (const float*)d_in[3];
    const float* sh   = (const float*)d_in[4];
    const float* Twc  = (const float*)d_in[5];
    float* out = (float*)d_out;

    char* ws = (char*)d_ws;
    float*  raw = (float*)ws;                        // 12*NG floats
    float4* s0  = (float4*)(ws + 49152);
    float4* s1  = (float4*)(ws + 65536);
    float4* s2  = (float4*)(ws + 81920);
    int*    nvp = (int*)(ws + 98304);
    float*  segbase = (float*)(ws + 98432);

    gs_prep <<<dim3(NG/64), dim3(64), 0, stream>>>(pos, rot, scl, opac, sh, Twc, raw);
    gs_sortc<<<dim3(NG/64), dim3(256), 0, stream>>>(raw, s0, s1, s2, nvp);

    int SEG = 0;
    for (int sgc = 8; sgc >= 1; sgc >>= 1) {
        size_t need = 98432 + (size_t)5 * sgc * NPIX * 4;
        if (need <= ws_size) { SEG = sgc; break; }
    }

    if (SEG > 0) {
        float* cr = segbase + 0ll * SEG * NPIX;
        float* cg = segbase + 1ll * SEG * NPIX;
        float* cb = segbase + 2ll * SEG * NPIX;
        float* cd = segbase + 3ll * SEG * NPIX;
        float* ct = segbase + 4ll * SEG * NPIX;
        gs_raster_seg<<<dim3(IMW/16, IMH/16, SEG), dim3(16, 16), 0, stream>>>(
            s0, s1, s2, nvp, SEG, cr, cg, cb, cd, ct);
        gs_combine<<<dim3((NPIX + 255)/256), dim3(256), 0, stream>>>(
            cr, cg, cb, cd, ct, SEG, out);
    } else {
        gs_raster_direct<<<dim3(IMW/16, IMH/16), dim3(16, 16), 0, stream>>>(
            s0, s1, s2, nvp, out);
    }
}

// Round 4
// 27.992 us; speedup vs baseline: 5.1235x; 1.1246x over previous
//
#include <hip/hip_runtime.h>
#include <hip/hip_bf16.h>

// ---- problem constants ----
#define NG 1024
#define IMW 256
#define IMH 192
#define NPIX (IMW*IMH)
#define FXc 220.0f
#define FYc 220.0f
#define CXc 128.0f
#define CYc 96.0f
#define NEARc 0.01f
#define FARc 10.0f
#define ALPHA_THRc 1e-5f

// SH constants
#define SH_C0 0.28209479177387814f
#define SH_C1 0.4886025119029199f
#define SH_C2_0 1.0925484305920792f
#define SH_C2_1 (-1.0925484305920792f)
#define SH_C2_2 0.31539156525252005f
#define SH_C2_3 (-1.0925484305920792f)
#define SH_C2_4 0.5462742152960396f
#define SH_C3_0 (-0.5900435899266435f)
#define SH_C3_1 2.890611442640554f
#define SH_C3_2 (-0.4570457994644658f)
#define SH_C3_3 0.3731763325901154f
#define SH_C3_4 (-0.4570457994644658f)
#define SH_C3_5 1.445305721320277f
#define SH_C3_6 (-0.5900435899266435f)

// ws layout (bytes):
//   g0 float4[NG] @ 0     : (u,v,A,B)
//   g1 float4[NG] @ 16384 : (C,op,r,g)
//   g2 float4[NG] @ 32768 : (b,z,rx,ry)   rx=-1e9 marks invalid

__global__ __launch_bounds__(64)
void gs_prep(const float* __restrict__ pos, const float* __restrict__ rot,
             const float* __restrict__ scl, const float* __restrict__ opac,
             const float* __restrict__ sh,  const float* __restrict__ Twc,
             float4* __restrict__ g0, float4* __restrict__ g1,
             float4* __restrict__ g2) {
    int i = blockIdx.x * 64 + threadIdx.x;
    if (i >= NG) return;

    float p0 = pos[i*3+0], p1 = pos[i*3+1], p2 = pos[i*3+2];
    float xc = Twc[0]*p0 + Twc[1]*p1 + Twc[2]*p2  + Twc[3];
    float yc = Twc[4]*p0 + Twc[5]*p1 + Twc[6]*p2  + Twc[7];
    float zc = Twc[8]*p0 + Twc[9]*p1 + Twc[10]*p2 + Twc[11];

    float az = fabsf(zc);
    const float xfac = fmaxf(CXc/FXc, (IMW - CXc)/FXc) * 1.1f;   // (1+MARGIN)
    const float yfac = fmaxf(CYc/FYc, (IMH - CYc)/FYc) * 1.1f;
    bool valid = (az > NEARc) && (az < FARc) &&
                 (fabsf(xc) < az * xfac) && (fabsf(yc) < az * yfac);

    float zs = (az < 1e-8f) ? 1e-8f : zc;
    float iz = 1.0f / zs;
    float u = FXc * xc * iz + CXc;
    float v = FYc * yc * iz + CYc;

    // quaternion -> R
    float qw = rot[i*4+0], qx = rot[i*4+1], qy = rot[i*4+2], qz = rot[i*4+3];
    float qn = sqrtf(qw*qw + qx*qx + qy*qy + qz*qz) + 1e-12f;
    float inq = 1.0f / qn;
    qw *= inq; qx *= inq; qy *= inq; qz *= inq;
    float R00 = 1.0f - 2.0f*(qy*qy + qz*qz);
    float R01 = 2.0f*(qx*qy - qw*qz);
    float R02 = 2.0f*(qx*qz + qw*qy);
    float R10 = 2.0f*(qx*qy + qw*qz);
    float R11 = 1.0f - 2.0f*(qx*qx + qz*qz);
    float R12 = 2.0f*(qy*qz - qw*qx);
    float R20 = 2.0f*(qx*qz - qw*qy);
    float R21 = 2.0f*(qy*qz + qw*qx);
    float R22 = 1.0f - 2.0f*(qx*qx + qy*qy);

    float s0 = expf(scl[i*3+0]);
    float s1 = expf(scl[i*3+1]);
    float s2 = expf(scl[i*3+2]);
    float M00 = R00*s0, M01 = R01*s1, M02 = R02*s2;
    float M10 = R10*s0, M11 = R11*s1, M12 = R12*s2;
    float M20 = R20*s0, M21 = R21*s1, M22 = R22*s2;

    // cov3d = M M^T (symmetric)
    float S00 = M00*M00 + M01*M01 + M02*M02;
    float S01 = M00*M10 + M01*M11 + M02*M12;
    float S02 = M00*M20 + M01*M21 + M02*M22;
    float S11 = M10*M10 + M11*M11 + M12*M12;
    float S12 = M10*M20 + M11*M21 + M12*M22;
    float S22 = M20*M20 + M21*M21 + M22*M22;

    // J (2x3), cov2d = J S J^T
    float j00 = FXc * iz,  j02 = -FXc * xc * iz * iz;
    float j11 = FYc * iz,  j12 = -FYc * yc * iz * iz;
    float c00 = j00*j00*S00 + 2.0f*j00*j02*S02 + j02*j02*S22 + 0.3f;
    float c01 = j00*j11*S01 + j00*j12*S02 + j02*j11*S12 + j02*j12*S22;
    float c11 = j11*j11*S11 + 2.0f*j11*j12*S12 + j12*j12*S22 + 0.3f;
    float det = fmaxf(c00*c11 - c01*c01, 1e-12f);
    float idet = 1.0f / det;
    float Ai = c11 * idet;
    float Bi = -c01 * idet;
    float Ci = c00 * idet;

    float op = valid ? opac[i] : 0.0f;

    // conservative extent: alpha >= thr  =>  q <= Q; ellipse q=Q extent:
    // rx = sqrt(Q*c00), ry = sqrt(Q*c11) (exact, from cov2d diagonal)
    float Q = fmaxf(2.0f * logf(fmaxf(op, 1e-20f) * 1e5f), 0.0f);
    float rx = valid ? (sqrtf(Q * c00) + 1e-3f) : -1e9f;
    float ry = valid ? (sqrtf(Q * c11) + 1e-3f) : -1e9f;

    // view dir
    float pn = sqrtf(xc*xc + yc*yc + zc*zc) + 1e-12f;
    float ipn = 1.0f / pn;
    float dx = xc*ipn, dy = yc*ipn, dz = zc*ipn;
    float xx = dx*dx, yy = dy*dy, zz = dz*dz;
    float xy = dx*dy, yz = dy*dz, xz = dx*dz;

    const float* s = sh + i*48;
    float col[3];
#pragma unroll
    for (int ch = 0; ch < 3; ++ch) {
        float c = SH_C0*s[0+ch] - SH_C1*dy*s[3+ch] + SH_C1*dz*s[6+ch] - SH_C1*dx*s[9+ch];
        c += SH_C2_0*xy*s[12+ch] + SH_C2_1*yz*s[15+ch] + SH_C2_2*(2.0f*zz-xx-yy)*s[18+ch]
           + SH_C2_3*xz*s[21+ch] + SH_C2_4*(xx-yy)*s[24+ch];
        c += SH_C3_0*dy*(3.0f*xx-yy)*s[27+ch] + SH_C3_1*xy*dz*s[30+ch]
           + SH_C3_2*dy*(4.0f*zz-xx-yy)*s[33+ch] + SH_C3_3*dz*(2.0f*zz-3.0f*xx-3.0f*yy)*s[36+ch]
           + SH_C3_4*dx*(4.0f*zz-xx-yy)*s[39+ch] + SH_C3_5*dz*(xx-yy)*s[42+ch]
           + SH_C3_6*dx*(xx-3.0f*yy)*s[45+ch];
        col[ch] = fminf(fmaxf(c + 0.5f, 0.0f), 1.0f);
    }

    g0[i] = make_float4(u, v, Ai, Bi);
    g1[i] = make_float4(Ci, op, col[0], col[1]);
    g2[i] = make_float4(col[2], zc, rx, ry);
}

// One 16x16 pixel tile per block. Cull all NG gaussians against the tile
// (LDS atomic append -- slot order is nondeterministic but the rank sort
// over unique keys makes the processed sequence, and thus the FP result,
// deterministic), rank-sort survivors by (z, index) in LDS, composite
// front-to-back with whole-wave early exit.
__global__ __launch_bounds__(256)
void gs_tile(const float4* __restrict__ g0, const float4* __restrict__ g1,
             const float4* __restrict__ g2, float* __restrict__ out) {
    __shared__ float4 sv0[NG], sv1[NG], sv2[NG];      // 48 KB
    __shared__ unsigned long long key[NG];            // 8 KB
    __shared__ unsigned short ord[NG];                // 2 KB
    __shared__ int scnt;

    int t = threadIdx.y * 16 + threadIdx.x;
    if (t == 0) scnt = 0;
    __syncthreads();

    float tx0 = (float)(blockIdx.x * 16) + 0.5f;
    float tx1 = tx0 + 15.0f;
    float ty0 = (float)(blockIdx.y * 16) + 0.5f;
    float ty1 = ty0 + 15.0f;

    // --- cull phase: 4 coalesced chunks of 256 ---
#pragma unroll
    for (int p = 0; p < 4; ++p) {
        int i = p * 256 + t;
        float4 a0 = g0[i];
        float4 a2 = g2[i];
        bool pass = (a0.x + a2.z >= tx0) && (a0.x - a2.z <= tx1) &&
                    (a0.y + a2.w >= ty0) && (a0.y - a2.w <= ty1);
        if (pass) {
            int pos = atomicAdd(&scnt, 1);
            sv0[pos] = a0;
            sv1[pos] = g1[i];
            sv2[pos] = a2;
            unsigned int zb = __float_as_uint(a2.y);
            zb = (zb & 0x80000000u) ? ~zb : (zb | 0x80000000u);  // monotone
            key[pos] = ((unsigned long long)zb << 32) | (unsigned int)(NG - 1 - i);
        }
    }
    __syncthreads();
    int M = scnt;

    // --- rank sort (ascending z, larger original index first on ties) ---
    for (int s = t; s < M; s += 256) {
        unsigned long long ks = key[s];
        int rank = 0;
        for (int j = 0; j < M; ++j)
            rank += (key[j] < ks) ? 1 : 0;
        ord[rank] = (unsigned short)s;
    }
    __syncthreads();

    // --- composite front-to-back ---
    float px = tx0 + (float)threadIdx.x;
    float py = ty0 + (float)threadIdx.y;
    float T = 1.0f;
    float cr = 0.0f, cg = 0.0f, cb = 0.0f, cd = 0.0f;

#pragma unroll 2
    for (int j = 0; j < M; ++j) {
        int slot = ord[j];
        float4 a0 = sv0[slot];
        float4 a1 = sv1[slot];
        float4 a2 = sv2[slot];
        float dx = px - a0.x;
        float dy = py - a0.y;
        float pw = -0.5f * (a0.z * dx * dx + a1.x * dy * dy) - a0.w * dx * dy;
        pw = fminf(pw, 0.0f);
        float alpha = fminf(0.99f, a1.y * __expf(pw));
        float aeff = (alpha >= ALPHA_THRc) ? alpha : 0.0f;
        float w = aeff * T;
        cr += w * a1.z;
        cg += w * a1.w;
        cb += w * a2.x;
        cd += w * a2.y;
        T *= 1.0f - aeff;
        if (__all(T < 1e-4f)) break;
    }

    int x = blockIdx.x * 16 + threadIdx.x;
    int y = blockIdx.y * 16 + threadIdx.y;
    int idx = y * IMW + x;
    out[idx*3 + 0] = cr;
    out[idx*3 + 1] = cg;
    out[idx*3 + 2] = cb;
    out[NPIX*3 + idx] = cd;
}

extern "C" void kernel_launch(void* const* d_in, const int* in_sizes, int n_in,
                              void* d_out, int out_size, void* d_ws, size_t ws_size,
                              hipStream_t stream) {
    const float* pos  = (const float*)d_in[0];
    const float* rot  = (const float*)d_in[1];
    const float* scl  = (const float*)d_in[2];
    const float* opac = (const float*)d_in[3];
    const float* sh   = (const float*)d_in[4];
    const float* Twc  = (const float*)d_in[5];
    float* out = (float*)d_out;

    char* ws = (char*)d_ws;
    float4* g0 = (float4*)ws;
    float4* g1 = (float4*)(ws + 16384);
    float4* g2 = (float4*)(ws + 32768);

    gs_prep<<<dim3(NG/64), dim3(64), 0, stream>>>(pos, rot, scl, opac, sh, Twc,
                                                  g0, g1, g2);
    gs_tile<<<dim3(IMW/16, IMH/16), dim3(16, 16), 0, stream>>>(g0, g1, g2, out);
}